// Round 1
// baseline (353.087 us; speedup 1.0000x reference)
//
#include <hip/hip_runtime.h>

// Problem: h_t = f_t*x_t + (1-f_t)*h_{t-1}, SEQ=1024, B*H=32768 channels, fp32.
// Layout [t][channel], channel fastest -> coalesced per-t loads.
//
// Round-2 rewrite: the previous single-pass kernel was latency-bound at 2 waves/CU
// (Occupancy 4.8%, HBM 29%, VALU 5% -- nothing busy). The recurrence is affine in h:
// over a chunk, h_out = A*h_in + B with A = prod(1-f), B = zero-init scan.
// Split time into 8 chunks of 128 -> 8x the waves, at the cost of re-reading f,x
// once (640 MB total vs 384 MB ideal). Both passes should be HBM-BW-bound.

#define SEQ 1024
#define NCH 32768          // B*H independent channels
#define NCHUNK 8
#define CLEN (SEQ / NCHUNK)  // 128 timesteps per chunk
#define TPB 256
#define UNR 8              // prefetch depth per register buffer

// Pass 1: per-chunk affine summaries (A, B) for chunks 0..NCHUNK-2.
// grid: (NCH/TPB, NCHUNK-1). 7*128 = 896 blocks * 4 waves = ~14 waves/CU.
__global__ __launch_bounds__(TPB) void fm_sum(const float* __restrict__ f,
                                              const float* __restrict__ x,
                                              float* __restrict__ Aw,
                                              float* __restrict__ Bw) {
    const int c = blockIdx.y;                       // chunk 0..6
    const int ch = blockIdx.x * TPB + threadIdx.x;  // channel
    const size_t base = (size_t)c * CLEN * NCH + ch;
    const float* fp = f + base;
    const float* xp = x + base;

    float A = 1.0f, Bv = 0.0f;
    float fA[UNR], xA[UNR], fB[UNR], xB[UNR];

#pragma unroll
    for (int j = 0; j < UNR; ++j) {
        fA[j] = fp[(size_t)j * NCH];
        xA[j] = xp[(size_t)j * NCH];
    }

    for (int t0 = 0; t0 < CLEN; t0 += 2 * UNR) {
#pragma unroll
        for (int j = 0; j < UNR; ++j) {
            fB[j] = fp[(size_t)(t0 + UNR + j) * NCH];
            xB[j] = xp[(size_t)(t0 + UNR + j) * NCH];
        }
#pragma unroll
        for (int j = 0; j < UNR; ++j) {
            Bv = fmaf(fA[j], xA[j] - Bv, Bv);   // B' = f*x + (1-f)*B
            A *= (1.0f - fA[j]);                // A' = (1-f)*A
        }
        if (t0 + 2 * UNR < CLEN) {
#pragma unroll
            for (int j = 0; j < UNR; ++j) {
                fA[j] = fp[(size_t)(t0 + 2 * UNR + j) * NCH];
                xA[j] = xp[(size_t)(t0 + 2 * UNR + j) * NCH];
            }
        }
#pragma unroll
        for (int j = 0; j < UNR; ++j) {
            Bv = fmaf(fB[j], xB[j] - Bv, Bv);
            A *= (1.0f - fB[j]);
        }
    }

    Aw[(size_t)c * NCH + ch] = A;
    Bw[(size_t)c * NCH + ch] = Bv;
}

// Pass 2: each chunk-c block composes its h_start from h0 and summaries of
// chunks < c (at most 7 affine composes -- cheap), then scans its 128 steps.
// grid: (NCH/TPB, NCHUNK). 1024 blocks * 4 waves = 16 waves/CU.
__global__ __launch_bounds__(TPB) void fm_scan(const float* __restrict__ f,
                                               const float* __restrict__ x,
                                               const float* __restrict__ h0,
                                               const float* __restrict__ Aw,
                                               const float* __restrict__ Bw,
                                               float* __restrict__ out) {
    const int c = blockIdx.y;                       // chunk 0..7
    const int ch = blockIdx.x * TPB + threadIdx.x;  // channel
    const size_t base = (size_t)c * CLEN * NCH + ch;
    const float* fp = f + base;
    const float* xp = x + base;
    float* op = out + base;

    // h_start for this chunk: h0 advanced through chunks 0..c-1.
    float h = h0[ch];
    for (int k = 0; k < c; ++k) {
        h = fmaf(Aw[(size_t)k * NCH + ch], h, Bw[(size_t)k * NCH + ch]);
    }

    float fA[UNR], xA[UNR], fB[UNR], xB[UNR];
#pragma unroll
    for (int j = 0; j < UNR; ++j) {
        fA[j] = fp[(size_t)j * NCH];
        xA[j] = xp[(size_t)j * NCH];
    }

    for (int t0 = 0; t0 < CLEN; t0 += 2 * UNR) {
#pragma unroll
        for (int j = 0; j < UNR; ++j) {
            fB[j] = fp[(size_t)(t0 + UNR + j) * NCH];
            xB[j] = xp[(size_t)(t0 + UNR + j) * NCH];
        }
#pragma unroll
        for (int j = 0; j < UNR; ++j) {
            h = fmaf(fA[j], xA[j] - h, h);       // h = f*x + (1-f)*h
            op[(size_t)(t0 + j) * NCH] = h;
        }
        if (t0 + 2 * UNR < CLEN) {
#pragma unroll
            for (int j = 0; j < UNR; ++j) {
                fA[j] = fp[(size_t)(t0 + 2 * UNR + j) * NCH];
                xA[j] = xp[(size_t)(t0 + 2 * UNR + j) * NCH];
            }
        }
#pragma unroll
        for (int j = 0; j < UNR; ++j) {
            h = fmaf(fB[j], xB[j] - h, h);
            op[(size_t)(t0 + UNR + j) * NCH] = h;
        }
    }
}

extern "C" void kernel_launch(void* const* d_in, const int* in_sizes, int n_in,
                              void* d_out, int out_size, void* d_ws, size_t ws_size,
                              hipStream_t stream) {
    const float* f  = (const float*)d_in[0];
    const float* x  = (const float*)d_in[1];
    const float* h0 = (const float*)d_in[2];
    float* out = (float*)d_out;

    // Workspace: (NCHUNK-1)*NCH floats for A, same for B -> 1.75 MB total.
    float* Aw = (float*)d_ws;
    float* Bw = Aw + (size_t)(NCHUNK - 1) * NCH;

    fm_sum<<<dim3(NCH / TPB, NCHUNK - 1), dim3(TPB), 0, stream>>>(f, x, Aw, Bw);
    fm_scan<<<dim3(NCH / TPB, NCHUNK), dim3(TPB), 0, stream>>>(f, x, h0, Aw, Bw, out);
}